// Round 2
// baseline (608.934 us; speedup 1.0000x reference)
//
#include <hip/hip_runtime.h>
#include <stdint.h>

// ---------------------------------------------------------------------------
// Self_postrans: pe(60ch NeRF enc) -> QKV (1x1 conv) -> softmax(sqrt(384)*Q^T K) -> P V
// B=8, N=2048, D=384, C=60. Inputs/outputs FP32 (per reference dtypes); internal
// math: fp32 accum MFMA with bf16 hi/lo splits (2% rel threshold permits).
// K1: pe + MFMA QKV, W and pe both hi/lo split (3-term MFMA, fp32-quality q,k).
// K2: flash attention, Q/K hi/lo bf16 split for S (3-term MFMA), bf16 P*V.
// ---------------------------------------------------------------------------

using s16x8 = __attribute__((ext_vector_type(8))) short;   // 8 bf16 = one MFMA frag
using f32x4 = __attribute__((ext_vector_type(4))) float;   // MFMA acc frag
typedef unsigned short u16;
typedef unsigned int   u32;

#define MFMA16 __builtin_amdgcn_mfma_f32_16x16x32_bf16

__device__ __forceinline__ u16 f2b(float x) {          // f32 -> bf16 RNE
  union { float f; u32 u; } v; v.f = x;
  return (u16)((v.u + 0x7fffu + ((v.u >> 16) & 1u)) >> 16);
}
__device__ __forceinline__ float b2f(u16 h) {
  union { float f; u32 u; } v; v.u = ((u32)h) << 16; return v.f;
}

// ws layout (bytes): bf16 staging tensors for the attention kernel
#define QH_OFF 0u
#define QL_OFF 12582912u
#define KH_OFF 25165824u
#define KL_OFF 37748736u
#define VV_OFF 50331648u
// total 62914560 bytes (60 MB)

// ---------------------------------------------------------------------------
// K1: pe + QKV.  grid 256 = (b=blk>>5, nt=blk&31), 256 threads (4 waves).
// GEMM: C[d][n] = sum_c W[d][c] * pe[n][c]  (K padded 60->64, zeros)
// A-frag: W[d = lane&15 (+16*rf)][c = quad*8+j], B-frag: pe[n = lane&15][c]
// C-frag: col = lane&15 -> n, row = quad*4+reg -> d
// ---------------------------------------------------------------------------
__global__ __launch_bounds__(256) void qkv_kernel(
    const float* __restrict__ pos,
    const float* __restrict__ Wq, const float* __restrict__ bq,
    const float* __restrict__ Wk, const float* __restrict__ bk,
    const float* __restrict__ Wv, const float* __restrict__ bv,
    u16* __restrict__ qh, u16* __restrict__ ql,
    u16* __restrict__ kh, u16* __restrict__ kl,
    u16* __restrict__ vv)
{
  const int tid = threadIdx.x;
  const int b = blockIdx.x >> 5, nt = blockIdx.x & 31;
  const int w = tid >> 6, lane = tid & 63, q15 = lane & 15, quad = lane >> 4;

  __shared__ __align__(16) u16 sWh[384 * 72];  // W hi, stride 72 (144B: 2-way banks, free)
  __shared__ __align__(16) u16 sWl[384 * 72];  // W lo
  __shared__ __align__(16) u16 sph[64 * 72];   // pe hi
  __shared__ __align__(16) u16 spl[64 * 72];   // pe lo
  // total 129024 B < 160 KB (single WG/CU; K1 is cheap)

  // ---- pe phase: 64 n x 60 ch (pad to 72 with zeros), hi/lo bf16 split ----
  for (int i = tid; i < 64 * 72; i += 256) {
    int n = i / 72, c = i % 72;
    u16 hi = 0, lo = 0;
    if (c < 60) {
      int coord = c / 20, j = c % 20, f = (j < 10) ? j : j - 10;
      float p = pos[(b * 3 + coord) * 2048 + nt * 64 + n];
      float x = p * (float)(1 << f);
      float s = (j < 10) ? sinf(x) : cosf(x);
      hi = f2b(s);
      lo = f2b(s - b2f(hi));
    }
    sph[i] = hi; spl[i] = lo;
  }

  const float* Wm[3] = {Wq, Wk, Wv};
  const float* bm[3] = {bq, bk, bv};

  for (int mat = 0; mat < 3; ++mat) {
    __syncthreads();                      // protect sW reuse
    const float* Wg = Wm[mat];
    for (int i = tid; i < 384 * 72; i += 256) {
      int dd = i / 72, c = i % 72;
      u16 hi = 0, lo = 0;
      if (c < 60) {
        float wv = Wg[dd * 60 + c];
        hi = f2b(wv);
        lo = f2b(wv - b2f(hi));
      }
      sWh[i] = hi; sWl[i] = lo;
    }
    __syncthreads();

    f32x4 acc[6][4];
    for (int rf = 0; rf < 6; ++rf)
      for (int nf = 0; nf < 4; ++nf) acc[rf][nf] = (f32x4){0.f, 0.f, 0.f, 0.f};

    for (int ks = 0; ks < 2; ++ks) {
      const int co = ks * 32 + quad * 8;
      s16x8 bh[4], bl[4];
      for (int nf = 0; nf < 4; ++nf) {
        bh[nf] = *(const s16x8*)&sph[(nf * 16 + q15) * 72 + co];
        bl[nf] = *(const s16x8*)&spl[(nf * 16 + q15) * 72 + co];
      }
      for (int rf = 0; rf < 6; ++rf) {    // wave owns d-strip w*96 .. +96
        s16x8 ah = *(const s16x8*)&sWh[(w * 96 + rf * 16 + q15) * 72 + co];
        s16x8 al = *(const s16x8*)&sWl[(w * 96 + rf * 16 + q15) * 72 + co];
        for (int nf = 0; nf < 4; ++nf) {
          // (Wh+Wl)(ph+pl) ~= Wh*ph + Wh*pl + Wl*ph  (Wl*pl ~ 2^-16 rel, dropped)
          acc[rf][nf] = MFMA16(ah, bh[nf], acc[rf][nf], 0, 0, 0);
          acc[rf][nf] = MFMA16(ah, bl[nf], acc[rf][nf], 0, 0, 0);
          acc[rf][nf] = MFMA16(al, bh[nf], acc[rf][nf], 0, 0, 0);
        }
      }
    }

    const float* bias = bm[mat];
    for (int rf = 0; rf < 6; ++rf) {
      int dbase = w * 96 + rf * 16 + quad * 4;
      float bi[4];
      for (int r = 0; r < 4; ++r) bi[r] = bias[dbase + r];
      for (int nf = 0; nf < 4; ++nf) {
        int n = nt * 64 + nf * 16 + q15;   // batch-local n
        float v0 = acc[rf][nf][0] + bi[0];
        float v1 = acc[rf][nf][1] + bi[1];
        float v2 = acc[rf][nf][2] + bi[2];
        float v3 = acc[rf][nf][3] + bi[3];
        if (mat == 2) {
          // V layout [b][d][n] (n contiguous) for PV B-frags
          vv[((size_t)b * 384 + dbase + 0) * 2048 + n] = f2b(v0);
          vv[((size_t)b * 384 + dbase + 1) * 2048 + n] = f2b(v1);
          vv[((size_t)b * 384 + dbase + 2) * 2048 + n] = f2b(v2);
          vv[((size_t)b * 384 + dbase + 3) * 2048 + n] = f2b(v3);
        } else {
          // Q/K layout [b][n][d] (d contiguous), hi/lo split for fp32-quality logits
          u16 h0 = f2b(v0), h1 = f2b(v1), h2 = f2b(v2), h3 = f2b(v3);
          u16 g0 = f2b(v0 - b2f(h0)), g1 = f2b(v1 - b2f(h1));
          u16 g2 = f2b(v2 - b2f(h2)), g3 = f2b(v3 - b2f(h3));
          size_t off = ((size_t)b * 2048 + n) * 384 + dbase;
          u16* ph = (mat == 0) ? qh : kh;
          u16* pl = (mat == 0) ? ql : kl;
          uint2 pk0; pk0.x = (u32)h0 | ((u32)h1 << 16); pk0.y = (u32)h2 | ((u32)h3 << 16);
          uint2 pk1; pk1.x = (u32)g0 | ((u32)g1 << 16); pk1.y = (u32)g2 | ((u32)g3 << 16);
          *(uint2*)&ph[off] = pk0;
          *(uint2*)&pl[off] = pk1;
        }
      }
    }
  }
}

// ---------------------------------------------------------------------------
// K2: flash attention. grid 256 = (b = blk&7 [XCD swizzle], qt = blk>>3).
// 4 waves. BM=64 q rows LDS-resident (hi+lo). kv tiles BN=64 (32 iters).
// S-phase: wave w computes S[(w&1)*32 .. +32][(w>>1)*32 .. +32], 3-term hi/lo MFMA.
// PV: wave w owns d-strip w*48 within each 192-d half; O[4rf][6cf] fp32 frags.
// ---------------------------------------------------------------------------
#define KLO_OFF (64 * 136)

__global__ __launch_bounds__(256) void attn_kernel(
    const u16* __restrict__ qh, const u16* __restrict__ ql,
    const u16* __restrict__ kh, const u16* __restrict__ kl,
    const u16* __restrict__ vv, float* __restrict__ out)
{
  const int tid = threadIdx.x;
  const int b = blockIdx.x & 7, qt = blockIdx.x >> 3;
  const int w = tid >> 6, lane = tid & 63, q15 = lane & 15, quad = lane >> 4;
  const int rw = (w & 1) * 32, cw = (w >> 1) * 32, ch = w >> 1;

  __shared__ __align__(16) u16 s_qh[64 * 392];    // Q hi, stride 392 (784B)
  __shared__ __align__(16) u16 s_ql[64 * 392];    // Q lo
  __shared__ __align__(16) u16 s_kv[2 * 64 * 136];// union: K hi/lo chunks | V half [192][72]
  __shared__ __align__(16) u16 s_p [64 * 72];     // P bf16, [n][m] stride 72
  __shared__ float s_m[64], s_l[64], s_al[64], s_pm[2][64], s_ps[2][64];

  // stage resident Q tile (hi+lo), padded stride 392
  {
    const u16* qs  = qh + ((size_t)b * 2048 + qt * 64) * 384;
    const u16* qls = ql + ((size_t)b * 2048 + qt * 64) * 384;
    for (int i = tid; i < 3072; i += 256) {
      int n = i / 48, c8 = (i % 48) * 8;
      *(uint4*)&s_qh[n * 392 + c8] = *(const uint4*)&qs [n * 384 + c8];
      *(uint4*)&s_ql[n * 392 + c8] = *(const uint4*)&qls[n * 384 + c8];
    }
  }
  if (tid < 64) { s_m[tid] = -1e30f; s_l[tid] = 0.f; }

  f32x4 o[4][6];
  for (int i = 0; i < 4; ++i)
    for (int j = 0; j < 6; ++j) o[i][j] = (f32x4){0.f, 0.f, 0.f, 0.f};

  for (int mt = 0; mt < 32; ++mt) {
    const size_t kb = ((size_t)b * 2048 + mt * 64) * 384;
    f32x4 sa[2][2];
    for (int i = 0; i < 2; ++i)
      for (int j = 0; j < 2; ++j) sa[i][j] = (f32x4){0.f, 0.f, 0.f, 0.f};

    // ---- S phase: K-dim 384 in 3 chunks of 128 ----
    for (int kc = 0; kc < 3; ++kc) {
      __syncthreads();   // prior users of s_kv done (also covers Q staging on mt=0)
      for (int i = tid; i < 1024; i += 256) {
        int m = i >> 4, c8 = (i & 15) * 8;
        *(uint4*)&s_kv[m * 136 + c8]           = *(const uint4*)&kh[kb + m * 384 + kc * 128 + c8];
        *(uint4*)&s_kv[KLO_OFF + m * 136 + c8] = *(const uint4*)&kl[kb + m * 384 + kc * 128 + c8];
      }
      __syncthreads();
      for (int ks = 0; ks < 4; ++ks) {
        const int ko = ks * 32 + quad * 8;
        const int kq = kc * 128 + ko;
        s16x8 ah0 = *(const s16x8*)&s_qh[(rw +      q15) * 392 + kq];
        s16x8 ah1 = *(const s16x8*)&s_qh[(rw + 16 + q15) * 392 + kq];
        s16x8 al0 = *(const s16x8*)&s_ql[(rw +      q15) * 392 + kq];
        s16x8 al1 = *(const s16x8*)&s_ql[(rw + 16 + q15) * 392 + kq];
        s16x8 bh0 = *(const s16x8*)&s_kv[(cw +      q15) * 136 + ko];
        s16x8 bh1 = *(const s16x8*)&s_kv[(cw + 16 + q15) * 136 + ko];
        s16x8 bl0 = *(const s16x8*)&s_kv[KLO_OFF + (cw +      q15) * 136 + ko];
        s16x8 bl1 = *(const s16x8*)&s_kv[KLO_OFF + (cw + 16 + q15) * 136 + ko];
        sa[0][0] = MFMA16(ah0, bh0, sa[0][0], 0, 0, 0);
        sa[0][0] = MFMA16(ah0, bl0, sa[0][0], 0, 0, 0);
        sa[0][0] = MFMA16(al0, bh0, sa[0][0], 0, 0, 0);
        sa[0][1] = MFMA16(ah0, bh1, sa[0][1], 0, 0, 0);
        sa[0][1] = MFMA16(ah0, bl1, sa[0][1], 0, 0, 0);
        sa[0][1] = MFMA16(al0, bh1, sa[0][1], 0, 0, 0);
        sa[1][0] = MFMA16(ah1, bh0, sa[1][0], 0, 0, 0);
        sa[1][0] = MFMA16(ah1, bl0, sa[1][0], 0, 0, 0);
        sa[1][0] = MFMA16(al1, bh0, sa[1][0], 0, 0, 0);
        sa[1][1] = MFMA16(ah1, bh1, sa[1][1], 0, 0, 0);
        sa[1][1] = MFMA16(ah1, bl1, sa[1][1], 0, 0, 0);
        sa[1][1] = MFMA16(al1, bh1, sa[1][1], 0, 0, 0);
      }
    }

    // ---- online softmax ----
    const float SC = 19.595917942265423f;   // / (384**-0.5)
    for (int rf = 0; rf < 2; ++rf)
      for (int cf = 0; cf < 2; ++cf) sa[rf][cf] *= SC;

    float rmx[2][4];
    for (int rf = 0; rf < 2; ++rf)
      for (int r = 0; r < 4; ++r)
        rmx[rf][r] = fmaxf(sa[rf][0][r], sa[rf][1][r]);
    for (int s = 1; s < 16; s <<= 1)
      for (int rf = 0; rf < 2; ++rf)
        for (int r = 0; r < 4; ++r)
          rmx[rf][r] = fmaxf(rmx[rf][r], __shfl_xor(rmx[rf][r], s, 64));
    if (q15 == 0)
      for (int rf = 0; rf < 2; ++rf)
        for (int r = 0; r < 4; ++r)
          s_pm[ch][rw + rf * 16 + quad * 4 + r] = rmx[rf][r];
    __syncthreads();
    if (tid < 64) {
      float mo = s_m[tid];
      float mn = fmaxf(mo, fmaxf(s_pm[0][tid], s_pm[1][tid]));
      s_al[tid] = __expf(mo - mn);
      s_m[tid] = mn;
    }
    __syncthreads();

    float rs[2][4] = {{0.f,0.f,0.f,0.f},{0.f,0.f,0.f,0.f}};
    for (int rf = 0; rf < 2; ++rf) {
      float mr[4];
      for (int r = 0; r < 4; ++r) mr[r] = s_m[rw + rf * 16 + quad * 4 + r];
      for (int cf = 0; cf < 2; ++cf)
        for (int r = 0; r < 4; ++r) {
          float p = __expf(sa[rf][cf][r] - mr[r]);
          rs[rf][r] += p;
          s_p[(rw + rf * 16 + quad * 4 + r) * 72 + cw + cf * 16 + q15] = f2b(p);
        }
    }
    for (int s = 1; s < 16; s <<= 1)
      for (int rf = 0; rf < 2; ++rf)
        for (int r = 0; r < 4; ++r)
          rs[rf][r] += __shfl_xor(rs[rf][r], s, 64);
    if (q15 == 0)
      for (int rf = 0; rf < 2; ++rf)
        for (int r = 0; r < 4; ++r)
          s_ps[ch][rw + rf * 16 + quad * 4 + r] = rs[rf][r];
    __syncthreads();
    if (tid < 64) s_l[tid] = s_l[tid] * s_al[tid] + s_ps[0][tid] + s_ps[1][tid];

    // rescale O by alpha (applies to previously accumulated tiles)
    for (int rfo = 0; rfo < 4; ++rfo) {
      float av[4];
      for (int r = 0; r < 4; ++r) av[r] = s_al[rfo * 16 + quad * 4 + r];
      for (int cf = 0; cf < 6; ++cf)
        for (int r = 0; r < 4; ++r)
          o[rfo][cf][r] *= av[r];
    }

    // ---- PV phase: V in two 192-d halves through the union region ----
    for (int h = 0; h < 2; ++h) {
      __syncthreads();   // prior s_kv users done (S MFMAs / previous half)
      const u16* vsrc = vv + ((size_t)b * 384 + h * 192) * 2048 + mt * 64;
      for (int i = tid; i < 1536; i += 256) {
        int dl = i >> 3, c8 = (i & 7) * 8;
        *(uint4*)&s_kv[dl * 72 + c8] = *(const uint4*)&vsrc[dl * 2048 + c8];
      }
      __syncthreads();
      for (int ks = 0; ks < 2; ++ks) {
        const int mo_ = ks * 32 + quad * 8;
        s16x8 pa0 = *(const s16x8*)&s_p[(     q15) * 72 + mo_];
        s16x8 pa1 = *(const s16x8*)&s_p[(16 + q15) * 72 + mo_];
        s16x8 pa2 = *(const s16x8*)&s_p[(32 + q15) * 72 + mo_];
        s16x8 pa3 = *(const s16x8*)&s_p[(48 + q15) * 72 + mo_];
        for (int cf = 0; cf < 3; ++cf) {
          s16x8 vb = *(const s16x8*)&s_kv[(w * 48 + cf * 16 + q15) * 72 + mo_];
          const int oc = h * 3 + cf;
          o[0][oc] = MFMA16(pa0, vb, o[0][oc], 0, 0, 0);
          o[1][oc] = MFMA16(pa1, vb, o[1][oc], 0, 0, 0);
          o[2][oc] = MFMA16(pa2, vb, o[2][oc], 0, 0, 0);
          o[3][oc] = MFMA16(pa3, vb, o[3][oc], 0, 0, 0);
        }
      }
    }
  }

  // ---- epilogue: out[b][d][n] = O[n][d] / l[n], fp32 output ----
  __syncthreads();
  if (tid < 64) s_al[tid] = 1.0f / s_l[tid];
  __syncthreads();
  for (int rfo = 0; rfo < 4; ++rfo) {
    float iv[4];
    for (int r = 0; r < 4; ++r) iv[r] = s_al[rfo * 16 + quad * 4 + r];
    for (int cf = 0; cf < 6; ++cf) {
      int d = (cf / 3) * 192 + w * 48 + (cf % 3) * 16 + q15;
      size_t off = ((size_t)b * 384 + d) * 2048 + qt * 64 + rfo * 16 + quad * 4;
      float4 r4;
      r4.x = o[rfo][cf][0] * iv[0];
      r4.y = o[rfo][cf][1] * iv[1];
      r4.z = o[rfo][cf][2] * iv[2];
      r4.w = o[rfo][cf][3] * iv[3];
      *(float4*)&out[off] = r4;
    }
  }
}

extern "C" void kernel_launch(void* const* d_in, const int* in_sizes, int n_in,
                              void* d_out, int out_size, void* d_ws, size_t ws_size,
                              hipStream_t stream) {
  const float* pos = (const float*)d_in[0];
  const float* Wq  = (const float*)d_in[1];
  const float* bq  = (const float*)d_in[2];
  const float* Wk  = (const float*)d_in[3];
  const float* bk  = (const float*)d_in[4];
  const float* Wv  = (const float*)d_in[5];
  const float* bv  = (const float*)d_in[6];

  char* ws = (char*)d_ws;
  u16* qh = (u16*)(ws + QH_OFF);
  u16* ql = (u16*)(ws + QL_OFF);
  u16* kh = (u16*)(ws + KH_OFF);
  u16* kl = (u16*)(ws + KL_OFF);
  u16* vv = (u16*)(ws + VV_OFF);

  qkv_kernel<<<256, 256, 0, stream>>>(pos, Wq, bq, Wk, bk, Wv, bv,
                                      qh, ql, kh, kl, vv);
  attn_kernel<<<256, 256, 0, stream>>>(qh, ql, kh, kl, vv, (float*)d_out);
}

// Round 4
// 546.113 us; speedup vs baseline: 1.1150x; 1.1150x over previous
//
#include <hip/hip_runtime.h>
#include <stdint.h>

// ---------------------------------------------------------------------------
// Self_postrans: pe(60ch) -> QKV -> softmax(sqrt(384) Q^T K) -> P V
// B=8, N=2048, D=384. fp32 I/O; internal fp16 MFMA (fp32 accum).
// K1: pe hi/lo fp16 + W hi/lo fp16, 3-term MFMA -> q,k fp32-quality.
//     Q stored fp16 (SC folded), K stored fp16 hi+lo, V fp16.
// K2: flash attn, 256 blocks x 2 waves x 32 q-rows. Q/O/softmax in registers.
//     K dbuf via swizzled global_load_lds; V single-buf; 2 barriers/tile,
//     no manual waitcnt (compiler-inserted vmcnt at barriers).
// ---------------------------------------------------------------------------

typedef unsigned short u16;
typedef unsigned int   u32;
using h16x8 = __attribute__((ext_vector_type(8))) _Float16;
using f32x4 = __attribute__((ext_vector_type(4))) float;

#define MF16(a,b,c) __builtin_amdgcn_mfma_f32_16x16x32_f16((a),(b),(c),0,0,0)

__device__ __forceinline__ u16 f2h_u(float x) { union { _Float16 h; u16 u; } v; v.h = (_Float16)x; return v.u; }
__device__ __forceinline__ float h2f(u16 u)   { union { _Float16 h; u16 u; } v; v.u = u; return (float)v.h; }

__device__ __forceinline__ float rmax16(float x) {
  x = fmaxf(x, __shfl_xor(x, 1, 16));
  x = fmaxf(x, __shfl_xor(x, 2, 16));
  x = fmaxf(x, __shfl_xor(x, 4, 16));
  x = fmaxf(x, __shfl_xor(x, 8, 16));
  return x;
}
__device__ __forceinline__ float rsum16(float x) {
  x += __shfl_xor(x, 1, 16);
  x += __shfl_xor(x, 2, 16);
  x += __shfl_xor(x, 4, 16);
  x += __shfl_xor(x, 8, 16);
  return x;
}

__device__ __forceinline__ void glds16(const void* g, u16* l) {
  __builtin_amdgcn_global_load_lds((const __attribute__((address_space(1))) u32*)g,
                                   (__attribute__((address_space(3))) u32*)l, 16, 0, 0);
}

// ws byte offsets (fp16 tensors)
#define QS_OFF 0u
#define KH_OFF 12582912u
#define KL_OFF 25165824u
#define VV_OFF 37748736u

#define SC 19.595917942265423f  // sqrt(384)

// ---------------------------------------------------------------------------
// K1: pe + QKV. grid 256 = (b = blk>>5, nt = blk&31), 256 thr (4 waves).
// q[d][n] = sum_c W[d][c] pe[n][c], K padded 60->64.
// ---------------------------------------------------------------------------
#define PH_E 0
#define PL_E 4608
#define WH_E 9216
#define WL_E 23040
#define TT_E 9216   // epilogue tiles overlay W region

__global__ __launch_bounds__(256, 1) void qkv_kernel(
    const float* __restrict__ pos,
    const float* __restrict__ Wq, const float* __restrict__ bq,
    const float* __restrict__ Wk, const float* __restrict__ bk,
    const float* __restrict__ Wv, const float* __restrict__ bv,
    u16* __restrict__ qs, u16* __restrict__ kh,
    u16* __restrict__ kl, u16* __restrict__ vv)
{
  const int tid = threadIdx.x;
  const int b = blockIdx.x >> 5, nt = blockIdx.x & 31;
  const int w = tid >> 6, lane = tid & 63, q15 = lane & 15, quad = lane >> 4;

  __shared__ __align__(16) u16 sm[36864];  // 72 KB

  // ---- pe: hi/lo fp16, accurate sin/cos (only ~18 evals/thread) ----
  for (int i = tid; i < 4608; i += 256) {
    int n = i / 72, c = i % 72;
    u16 hi = 0, lo = 0;
    if (c < 60) {
      int coord = c / 20, j = c % 20, f = (j < 10) ? j : j - 10;
      float p = pos[(b * 3 + coord) * 2048 + nt * 64 + n];
      float x = p * (float)(1 << f);
      float s = (j < 10) ? sinf(x) : cosf(x);
      hi = f2h_u(s);
      lo = f2h_u(s - h2f(hi));
    }
    sm[PH_E + i] = hi; sm[PL_E + i] = lo;
  }

  for (int mat = 0; mat < 3; ++mat) {
    const float* Wg = (mat == 0) ? Wq : ((mat == 1) ? Wk : Wv);
    const float* bg = (mat == 0) ? bq : ((mat == 1) ? bk : bv);
    for (int h = 0; h < 2; ++h) {
      __syncthreads();
      // stage W half (192 d) hi/lo fp16
      for (int i = tid; i < 13824; i += 256) {
        int dd = i / 72, c = i % 72;
        u16 hi = 0, lo = 0;
        if (c < 60) {
          float v = Wg[(h * 192 + dd) * 60 + c];
          hi = f2h_u(v);
          lo = f2h_u(v - h2f(hi));
        }
        sm[WH_E + i] = hi; sm[WL_E + i] = lo;
      }
      __syncthreads();

      f32x4 acc[3][4];
#pragma unroll
      for (int rf = 0; rf < 3; ++rf)
#pragma unroll
        for (int nf = 0; nf < 4; ++nf) acc[rf][nf] = (f32x4){0.f, 0.f, 0.f, 0.f};

#pragma unroll
      for (int ks = 0; ks < 2; ++ks) {
        const int co = ks * 32 + quad * 8;
        h16x8 bh[4], bl[4];
#pragma unroll
        for (int nf = 0; nf < 4; ++nf) {
          bh[nf] = *(const h16x8*)&sm[PH_E + (nf * 16 + q15) * 72 + co];
          bl[nf] = *(const h16x8*)&sm[PL_E + (nf * 16 + q15) * 72 + co];
        }
#pragma unroll
        for (int rf = 0; rf < 3; ++rf) {
          h16x8 ah = *(const h16x8*)&sm[WH_E + (w * 48 + rf * 16 + q15) * 72 + co];
          h16x8 al = *(const h16x8*)&sm[WL_E + (w * 48 + rf * 16 + q15) * 72 + co];
#pragma unroll
          for (int nf = 0; nf < 4; ++nf) {
            acc[rf][nf] = MF16(ah, bh[nf], acc[rf][nf]);
            acc[rf][nf] = MF16(ah, bl[nf], acc[rf][nf]);
            acc[rf][nf] = MF16(al, bh[nf], acc[rf][nf]);
          }
        }
      }

      // bias (+SC fold for Q)
#pragma unroll
      for (int rf = 0; rf < 3; ++rf) {
#pragma unroll
        for (int r = 0; r < 4; ++r) {
          float bi = bg[h * 192 + w * 48 + rf * 16 + quad * 4 + r];
#pragma unroll
          for (int nf = 0; nf < 4; ++nf) {
            float v = acc[rf][nf][r] + bi;
            acc[rf][nf][r] = (mat == 0) ? v * SC : v;
          }
        }
      }
      __syncthreads();  // W region -> tile reuse

      if (mat == 2) {
        // V: transposed tile [192 d][72 n], then coalesced copy
#pragma unroll
        for (int rf = 0; rf < 3; ++rf)
#pragma unroll
          for (int nf = 0; nf < 4; ++nf)
#pragma unroll
            for (int r = 0; r < 4; ++r)
              sm[TT_E + (w * 48 + rf * 16 + quad * 4 + r) * 72 + nf * 16 + q15] = f2h_u(acc[rf][nf][r]);
        __syncthreads();
        for (int c = tid; c < 1536; c += 256) {
          int d = c >> 3, k = c & 7;
          *(uint4*)&vv[((size_t)(b * 384 + h * 192 + d)) * 2048 + nt * 64 + k * 8] =
              *(const uint4*)&sm[TT_E + d * 72 + k * 8];
        }
      } else {
        // Q/K: tile [64 n][200], coalesced copy; K adds lo pass
        const int npass = (mat == 1) ? 2 : 1;
        for (int pass = 0; pass < npass; ++pass) {
#pragma unroll
          for (int rf = 0; rf < 3; ++rf)
#pragma unroll
            for (int nf = 0; nf < 4; ++nf)
#pragma unroll
              for (int r = 0; r < 4; ++r) {
                float v = acc[rf][nf][r];
                u16 out16 = (pass == 0) ? f2h_u(v) : f2h_u(v - h2f(f2h_u(v)));
                sm[TT_E + (nf * 16 + q15) * 200 + (w * 48 + rf * 16 + quad * 4 + r)] = out16;
              }
          __syncthreads();
          u16* dst = (mat == 0) ? qs : ((pass == 0) ? kh : kl);
          for (int c = tid; c < 1536; c += 256) {
            int n = c / 24, k = c % 24;
            *(uint4*)&dst[((size_t)(b * 2048 + nt * 64 + n)) * 384 + h * 192 + k * 8] =
                *(const uint4*)&sm[TT_E + n * 200 + k * 8];
          }
          if (pass + 1 < npass) __syncthreads();
        }
      }
    }
  }
}

// ---------------------------------------------------------------------------
// K2: flash attention. grid 256 = (b = blk&7, qt = blk>>3), 128 thr (2 waves).
// wave w owns q rows qt*64 + w*32 .. +32 (2 MFMA strips). Q/O/m/l in regs.
// LDS (u16 elems): KH0@0 KL0@12288 KH1@24576 KL1@36864 (768B rows, col^=(row&7))
//                  V@49152 (384 rows x 80B pad)  P@64512 (2 waves x 32 x 80B)
// ---------------------------------------------------------------------------
#define KHB(c) ((c) ? 24576 : 0)
#define KLB(c) ((c) ? 36864 : 12288)
#define VO_E 49152
#define PO_E 64512

__global__ __launch_bounds__(128, 1) void attn_kernel(
    const u16* __restrict__ qs, const u16* __restrict__ kh,
    const u16* __restrict__ kl, const u16* __restrict__ vv,
    float* __restrict__ outp)
{
  const int tid = threadIdx.x;
  const int b = blockIdx.x & 7, qt = blockIdx.x >> 3;
  const int w = tid >> 6, lane = tid & 63, q15 = lane & 15, quad = lane >> 4;

  __shared__ __align__(16) u16 smem[67072];  // 134144 B

  // K-staging lane byte offsets within a 4-row (3072 B) group: kfo[j*2+p]
  int kfo[6];
#pragma unroll
  for (int j = 0; j < 3; ++j)
#pragma unroll
    for (int p = 0; p < 2; ++p) {
      int sub = j * 1024 + lane * 16;
      int r0 = sub / 768;                 // row within group
      int cp = (sub - r0 * 768) >> 4;     // linear 16B col
      int rx = (4 * p + r0) & 7;          // == (global row) & 7
      int cl = (cp & ~7) | ((cp & 7) ^ rx);
      kfo[j * 2 + p] = r0 * 768 + cl * 16;
    }

  // Q fragments in registers (fp16, SC-folded)
  h16x8 qf[2][12];
#pragma unroll
  for (int s = 0; s < 2; ++s)
#pragma unroll
    for (int ks = 0; ks < 12; ++ks)
      qf[s][ks] = *(const h16x8*)&qs[((size_t)(b * 2048 + qt * 64 + w * 32 + s * 16 + q15)) * 384
                                     + ks * 32 + quad * 8];

  // prologue: stage K tile 0 into buf0
  {
    const char* kht = (const char*)(kh + (size_t)(b * 2048) * 384);
    const char* klt = (const char*)(kl + (size_t)(b * 2048) * 384);
#pragma unroll
    for (int t = 0; t < 12; ++t) {
      const int m = w * 4 + t / 3;
      const int off = m * 3072 + kfo[(t % 3) * 2 + ((t / 3) & 1)];
      glds16(kht + off, &smem[KHB(0) + (w * 12 + t) * 512]);
      glds16(klt + off, &smem[KLB(0) + (w * 12 + t) * 512]);
    }
  }
  __syncthreads();

  f32x4 o[2][24];
#pragma unroll
  for (int s = 0; s < 2; ++s)
#pragma unroll
    for (int cf = 0; cf < 24; ++cf) o[s][cf] = (f32x4){0.f, 0.f, 0.f, 0.f};
  float mo[2][4], ll[2][4];
#pragma unroll
  for (int s = 0; s < 2; ++s)
#pragma unroll
    for (int r = 0; r < 4; ++r) { mo[s][r] = -1e30f; ll[s][r] = 0.f; }

  for (int mt = 0; mt < 64; ++mt) {
    const int cur = mt & 1;

    // ---- stage V(mt) (15 DMA/wave; 80B-padded rows, c==4 slots land in pad) ----
    {
      const char* vt = (const char*)(vv + (size_t)b * 384 * 2048 + mt * 32);
#pragma unroll
      for (int t = 0; t < 15; ++t) {
        int i = w * 15 + t;
        int u = 64 * i + lane;
        int row = u / 5;
        int c = u - row * 5; c = (c > 3) ? 3 : c;
        glds16(vt + row * 4096 + c * 16, &smem[VO_E + i * 512]);
      }
    }
    // ---- stage K(mt+1) into other buffer (24 DMA/wave) ----
    {
      const int nmt = (mt + 1) & 63, nb = cur ^ 1;
      const char* kht = (const char*)(kh + (size_t)(b * 2048 + nmt * 32) * 384);
      const char* klt = (const char*)(kl + (size_t)(b * 2048 + nmt * 32) * 384);
#pragma unroll
      for (int t = 0; t < 12; ++t) {
        const int m = w * 4 + t / 3;
        const int off = m * 3072 + kfo[(t % 3) * 2 + ((t / 3) & 1)];
        glds16(kht + off, &smem[KHB(nb) + (w * 12 + t) * 512]);
        glds16(klt + off, &smem[KLB(nb) + (w * 12 + t) * 512]);
      }
    }

    // ---- S phase: sa[strip][cf] = q . (kh + kl), fp32 accum ----
    f32x4 sa[2][2];
#pragma unroll
    for (int s = 0; s < 2; ++s)
#pragma unroll
      for (int cf = 0; cf < 2; ++cf) sa[s][cf] = (f32x4){0.f, 0.f, 0.f, 0.f};
#pragma unroll
    for (int ks = 0; ks < 12; ++ks) {
      h16x8 bh[2], bl[2];
#pragma unroll
      for (int cf = 0; cf < 2; ++cf) {
        const int row = cf * 16 + q15;
        const int cp = ((ks >> 1) * 8) | ((((ks & 1) * 4) | quad) ^ (row & 7));
        const int eo = row * 384 + cp * 8;   // u16 elems (row stride 768 B)
        bh[cf] = *(const h16x8*)&smem[KHB(cur) + eo];
        bl[cf] = *(const h16x8*)&smem[KLB(cur) + eo];
      }
#pragma unroll
      for (int s = 0; s < 2; ++s)
#pragma unroll
        for (int cf = 0; cf < 2; ++cf) {
          sa[s][cf] = MF16(qf[s][ks], bh[cf], sa[s][cf]);
          sa[s][cf] = MF16(qf[s][ks], bl[cf], sa[s][cf]);
        }
    }

    // ---- online softmax (registers + shfl) ----
    float al[2][4], ps[2][2][4];
#pragma unroll
    for (int s = 0; s < 2; ++s)
#pragma unroll
      for (int r = 0; r < 4; ++r) {
        float mx = rmax16(fmaxf(sa[s][0][r], sa[s][1][r]));
        float mn = fmaxf(mo[s][r], mx);
        al[s][r] = __expf(mo[s][r] - mn);
        mo[s][r] = mn;
      }
#pragma unroll
    for (int s = 0; s < 2; ++s)
#pragma unroll
      for (int r = 0; r < 4; ++r) {
        ps[s][0][r] = __expf(sa[s][0][r] - mo[s][r]);
        ps[s][1][r] = __expf(sa[s][1][r] - mo[s][r]);
        float rs = rsum16(ps[s][0][r] + ps[s][1][r]);
        ll[s][r] = ll[s][r] * al[s][r] + rs;
      }
    // P -> LDS (wave-private region, stride 40 elems)
#pragma unroll
    for (int s = 0; s < 2; ++s)
#pragma unroll
      for (int cf = 0; cf < 2; ++cf)
#pragma unroll
        for (int r = 0; r < 4; ++r)
          smem[PO_E + w * 1280 + (s * 16 + quad * 4 + r) * 40 + cf * 16 + q15] = f2h_u(ps[s][cf][r]);
    // O rescale
#pragma unroll
    for (int s = 0; s < 2; ++s)
#pragma unroll
      for (int cf = 0; cf < 24; ++cf)
#pragma unroll
        for (int r = 0; r < 4; ++r) o[s][cf][r] *= al[s][r];

    __syncthreads();  // B: V(mt) DMA drained; K(mt+1) also (early, acceptable)

    // ---- PV ----
    h16x8 pa[2];
    pa[0] = *(const h16x8*)&smem[PO_E + w * 1280 + q15 * 40 + quad * 8];
    pa[1] = *(const h16x8*)&smem[PO_E + w * 1280 + (16 + q15) * 40 + quad * 8];
#pragma unroll
    for (int cf = 0; cf < 24; ++cf) {
      h16x8 vb = *(const h16x8*)&smem[VO_E + (cf * 16 + q15) * 40 + quad * 8];
      o[0][cf] = MF16(pa[0], vb, o[0][cf]);
      o[1][cf] = MF16(pa[1], vb, o[1][cf]);
    }

    __syncthreads();  // A: all PV reads done before next tile's V DMA
  }

  // ---- epilogue: out[b][d][n] = O/l via LDS transpose (fp32) ----
  float* ot = (float*)smem;
  float inv[2][4];
#pragma unroll
  for (int s = 0; s < 2; ++s)
#pragma unroll
    for (int r = 0; r < 4; ++r) inv[s][r] = 1.0f / ll[s][r];
#pragma unroll
  for (int s = 0; s < 2; ++s)
#pragma unroll
    for (int cf = 0; cf < 24; ++cf)
#pragma unroll
      for (int r = 0; r < 4; ++r)
        ot[(cf * 16 + q15) * 68 + (w * 32 + s * 16 + quad * 4 + r)] = o[s][cf][r] * inv[s][r];
  __syncthreads();
  for (int c = tid; c < 6144; c += 128) {
    int d = c >> 4, n8 = c & 15;
    *(float4*)&outp[((size_t)(b * 384 + d)) * 2048 + qt * 64 + n8 * 4] =
        *(const float4*)&ot[d * 68 + n8 * 4];
  }
}

extern "C" void kernel_launch(void* const* d_in, const int* in_sizes, int n_in,
                              void* d_out, int out_size, void* d_ws, size_t ws_size,
                              hipStream_t stream) {
  const float* pos = (const float*)d_in[0];
  const float* Wq  = (const float*)d_in[1];
  const float* bq  = (const float*)d_in[2];
  const float* Wk  = (const float*)d_in[3];
  const float* bk  = (const float*)d_in[4];
  const float* Wv  = (const float*)d_in[5];
  const float* bv  = (const float*)d_in[6];

  char* ws = (char*)d_ws;
  u16* qs = (u16*)(ws + QS_OFF);
  u16* kh = (u16*)(ws + KH_OFF);
  u16* kl = (u16*)(ws + KL_OFF);
  u16* vv = (u16*)(ws + VV_OFF);

  qkv_kernel<<<256, 256, 0, stream>>>(pos, Wq, bq, Wk, bk, Wv, bv, qs, kh, kl, vv);
  attn_kernel<<<256, 128, 0, stream>>>(qs, kh, kl, vv, (float*)d_out);
}

// Round 5
// 347.303 us; speedup vs baseline: 1.7533x; 1.5724x over previous
//
#include <hip/hip_runtime.h>
#include <stdint.h>

// ---------------------------------------------------------------------------
// Self_postrans: pe(60ch) -> QKV -> softmax(sqrt(384) Q^T K) -> P V
// B=8, N=2048, D=384. fp32 I/O; internal fp16 MFMA (fp32 accum).
// K1 (grid 512 = b x nt x h-half): pe fp16 hi/lo via __sinf, W fp16 hi/lo,
//     3-term MFMA. Outputs: Q hi+lo (SC folded), K fp16, V fp16 [d][n].
// K2 (grid 512 x 128 thr, 2 blocks/CU): flash attn, 2 waves x 16 q-rows.
//     Q hi/lo + O + softmax in regs; K single-fp16 dbuf via swizzled
//     global_load_lds; V swizzled 64B rows; 2 barriers/tile.
// ---------------------------------------------------------------------------

typedef unsigned short u16;
typedef unsigned int   u32;
using h16x8 = __attribute__((ext_vector_type(8))) _Float16;
using f32x4 = __attribute__((ext_vector_type(4))) float;

#define MF16(a,b,c) __builtin_amdgcn_mfma_f32_16x16x32_f16((a),(b),(c),0,0,0)

__device__ __forceinline__ u16 f2h_u(float x) { union { _Float16 h; u16 u; } v; v.h = (_Float16)x; return v.u; }
__device__ __forceinline__ float h2f(u16 u)   { union { _Float16 h; u16 u; } v; v.u = u; return (float)v.h; }

__device__ __forceinline__ float rmax16(float x) {
  x = fmaxf(x, __shfl_xor(x, 1, 16));
  x = fmaxf(x, __shfl_xor(x, 2, 16));
  x = fmaxf(x, __shfl_xor(x, 4, 16));
  x = fmaxf(x, __shfl_xor(x, 8, 16));
  return x;
}
__device__ __forceinline__ float rsum16(float x) {
  x += __shfl_xor(x, 1, 16);
  x += __shfl_xor(x, 2, 16);
  x += __shfl_xor(x, 4, 16);
  x += __shfl_xor(x, 8, 16);
  return x;
}

__device__ __forceinline__ void glds16(const void* g, u16* l) {
  __builtin_amdgcn_global_load_lds((const __attribute__((address_space(1))) u32*)g,
                                   (__attribute__((address_space(3))) u32*)l, 16, 0, 0);
}

// ws byte offsets (fp16 tensors, 12.58 MB each)
#define QH_OFF 0u
#define QL_OFF 12582912u
#define KH_OFF 25165824u
#define VV_OFF 37748736u

#define SC 19.595917942265423f  // sqrt(384)

// ---------------------------------------------------------------------------
// K1: grid 512 = (b = blk&7, nt = (blk>>3)&31, h = blk>>8). 256 thr, 2 blk/CU.
// ---------------------------------------------------------------------------
#define PH_E 0
#define PL_E 4608
#define WH_E 9216
#define WL_E 23040
#define TT_E 9216   // epilogue tiles overlay WH region (13824 elems)

__global__ __launch_bounds__(256, 2) void qkv_kernel(
    const float* __restrict__ pos,
    const float* __restrict__ Wq, const float* __restrict__ bq,
    const float* __restrict__ Wk, const float* __restrict__ bk,
    const float* __restrict__ Wv, const float* __restrict__ bv,
    u16* __restrict__ qh, u16* __restrict__ ql,
    u16* __restrict__ kh, u16* __restrict__ vv)
{
  const int tid = threadIdx.x;
  const int b = blockIdx.x & 7, nt = (blockIdx.x >> 3) & 31, h = blockIdx.x >> 8;
  const int w = tid >> 6, q15 = tid & 15, quad = (tid & 63) >> 4;

  __shared__ __align__(16) u16 sm[36864];  // 72 KB -> 2 blocks/CU

  // ---- pe: hi/lo fp16; __sinf/__cosf (phase err ~2e-4 rad at |x|<2500) ----
  for (int i = tid; i < 4608; i += 256) {
    int n = i / 72, c = i % 72;
    u16 hi = 0, lo = 0;
    if (c < 60) {
      int coord = c / 20, j = c % 20, f = (j < 10) ? j : j - 10;
      float p = pos[(b * 3 + coord) * 2048 + nt * 64 + n];
      float x = p * (float)(1 << f);
      float s = (j < 10) ? __sinf(x) : __cosf(x);
      hi = f2h_u(s);
      lo = f2h_u(s - h2f(hi));
    }
    sm[PH_E + i] = hi; sm[PL_E + i] = lo;
  }

  for (int mat = 0; mat < 3; ++mat) {
    const float* Wg = (mat == 0) ? Wq : ((mat == 1) ? Wk : Wv);
    const float* bg = (mat == 0) ? bq : ((mat == 1) ? bk : bv);
    __syncthreads();   // pe done (iter 0) / prior epilogue copies done
    for (int i = tid; i < 13824; i += 256) {
      int dd = i / 72, c = i % 72;
      u16 hi = 0, lo = 0;
      if (c < 60) {
        float v = Wg[(h * 192 + dd) * 60 + c];
        hi = f2h_u(v);
        lo = f2h_u(v - h2f(hi));
      }
      sm[WH_E + i] = hi; sm[WL_E + i] = lo;
    }
    __syncthreads();

    f32x4 acc[3][4];
#pragma unroll
    for (int rf = 0; rf < 3; ++rf)
#pragma unroll
      for (int nf = 0; nf < 4; ++nf) acc[rf][nf] = (f32x4){0.f, 0.f, 0.f, 0.f};

#pragma unroll
    for (int ks = 0; ks < 2; ++ks) {
      const int co = ks * 32 + quad * 8;
      h16x8 bh[4], bl[4];
#pragma unroll
      for (int nf = 0; nf < 4; ++nf) {
        bh[nf] = *(const h16x8*)&sm[PH_E + (nf * 16 + q15) * 72 + co];
        bl[nf] = *(const h16x8*)&sm[PL_E + (nf * 16 + q15) * 72 + co];
      }
#pragma unroll
      for (int rf = 0; rf < 3; ++rf) {
        h16x8 ah = *(const h16x8*)&sm[WH_E + (w * 48 + rf * 16 + q15) * 72 + co];
        h16x8 al = *(const h16x8*)&sm[WL_E + (w * 48 + rf * 16 + q15) * 72 + co];
#pragma unroll
        for (int nf = 0; nf < 4; ++nf) {
          acc[rf][nf] = MF16(ah, bh[nf], acc[rf][nf]);
          acc[rf][nf] = MF16(ah, bl[nf], acc[rf][nf]);
          acc[rf][nf] = MF16(al, bh[nf], acc[rf][nf]);
        }
      }
    }

#pragma unroll
    for (int rf = 0; rf < 3; ++rf)
#pragma unroll
      for (int r = 0; r < 4; ++r) {
        float bi = bg[h * 192 + w * 48 + rf * 16 + quad * 4 + r];
#pragma unroll
        for (int nf = 0; nf < 4; ++nf) {
          float v = acc[rf][nf][r] + bi;
          acc[rf][nf][r] = (mat == 0) ? v * SC : v;
        }
      }
    __syncthreads();   // W reads done; TT may overwrite

    if (mat == 2) {
      // V: transposed tile [192 d][72 n] -> vv[b][d][n]
#pragma unroll
      for (int rf = 0; rf < 3; ++rf)
#pragma unroll
        for (int nf = 0; nf < 4; ++nf)
#pragma unroll
          for (int r = 0; r < 4; ++r)
            sm[TT_E + (w * 48 + rf * 16 + quad * 4 + r) * 72 + nf * 16 + q15] = f2h_u(acc[rf][nf][r]);
      __syncthreads();
      for (int c = tid; c < 1536; c += 256) {
        int d = c >> 3, k = c & 7;
        *(uint4*)&vv[((size_t)(b * 384 + h * 192 + d)) * 2048 + nt * 64 + k * 8] =
            *(const uint4*)&sm[TT_E + d * 72 + k * 8];
      }
    } else {
      const int npass = (mat == 0) ? 2 : 1;
      for (int pass = 0; pass < npass; ++pass) {
#pragma unroll
        for (int rf = 0; rf < 3; ++rf)
#pragma unroll
          for (int nf = 0; nf < 4; ++nf)
#pragma unroll
            for (int r = 0; r < 4; ++r) {
              float v = acc[rf][nf][r];
              u16 o16 = (pass == 0) ? f2h_u(v) : f2h_u(v - h2f(f2h_u(v)));
              sm[TT_E + (nf * 16 + q15) * 200 + (w * 48 + rf * 16 + quad * 4 + r)] = o16;
            }
        __syncthreads();
        u16* dst = (mat == 1) ? kh : ((pass == 0) ? qh : ql);
        for (int c = tid; c < 1536; c += 256) {
          int n = c / 24, k = c % 24;
          *(uint4*)&dst[((size_t)(b * 2048 + nt * 64 + n)) * 384 + h * 192 + k * 8] =
              *(const uint4*)&sm[TT_E + n * 200 + k * 8];
        }
        if (pass + 1 < npass) __syncthreads();
      }
    }
  }
}

// ---------------------------------------------------------------------------
// K2: flash attn. grid 512 = (b = blk&7, qt = blk>>3), 128 thr, 2 blocks/CU.
// LDS (u16 elems): K0@0, K1@12288 (32 rows x 768B, chunk^=(row&7));
//                  V@24576 (384 rows x 64B, chunk^=(d&3)); P@36864 (2x16x40).
// ---------------------------------------------------------------------------
#define KE(buf) ((buf) ? 12288 : 0)
#define VE 24576
#define PE 36864

__global__ __launch_bounds__(128, 1) void attn_kernel(
    const u16* __restrict__ qhp, const u16* __restrict__ qlp,
    const u16* __restrict__ khp, const u16* __restrict__ vvp,
    float* __restrict__ outp)
{
  const int tid = threadIdx.x;
  const int b = blockIdx.x & 7, qt = blockIdx.x >> 3;
  const int w = tid >> 6, lane = tid & 63, q15 = lane & 15, quad = lane >> 4;

  __shared__ __align__(16) u16 smem[38144];  // 76288 B -> 2 blocks/CU

  // K-staging source offsets within a 4-row (3072 B) group
  int kfo[6];
#pragma unroll
  for (int j = 0; j < 3; ++j)
#pragma unroll
    for (int p = 0; p < 2; ++p) {
      int sub = j * 1024 + lane * 16;
      int r0 = sub / 768;
      int cp = (sub - r0 * 768) >> 4;
      int rx = (4 * p + r0) & 7;                // == (global row) & 7
      int cl = (cp & ~7) | ((cp & 7) ^ rx);
      kfo[j * 2 + p] = r0 * 768 + cl * 16;
    }

  // Q hi/lo fragments in registers (fp16, SC folded)
  h16x8 qfh[12], qfl[12];
  {
    const size_t qr = ((size_t)(b * 2048 + qt * 32 + w * 16 + q15)) * 384;
#pragma unroll
    for (int ks = 0; ks < 12; ++ks) {
      qfh[ks] = *(const h16x8*)&qhp[qr + ks * 32 + quad * 8];
      qfl[ks] = *(const h16x8*)&qlp[qr + ks * 32 + quad * 8];
    }
  }

  // prologue: K tile 0 -> buf 0 (12 DMA/wave)
  {
    const char* kt = (const char*)(khp + (size_t)(b * 2048) * 384);
#pragma unroll
    for (int t = 0; t < 12; ++t) {
      int g = w * 4 + t / 3;
      glds16(kt + g * 3072 + kfo[(t % 3) * 2 + (g & 1)], &smem[KE(0) + (w * 12 + t) * 512]);
    }
  }
  __syncthreads();

  f32x4 o[24];
#pragma unroll
  for (int cf = 0; cf < 24; ++cf) o[cf] = (f32x4){0.f, 0.f, 0.f, 0.f};
  float mo[4], ll[4];
#pragma unroll
  for (int r = 0; r < 4; ++r) { mo[r] = -1e30f; ll[r] = 0.f; }

  for (int mt = 0; mt < 64; ++mt) {
    const int cur = mt & 1;

    // ---- stage V(mt): 384 rows x 64B, source-swizzled (12 DMA/wave) ----
    {
      const char* vt = (const char*)(vvp + (size_t)b * 384 * 2048 + mt * 32);
#pragma unroll
      for (int t = 0; t < 12; ++t) {
        int i = w * 12 + t;
        int d = i * 16 + (lane >> 2), s = lane & 3;
        glds16(vt + d * 4096 + ((s ^ (d & 3)) * 16), &smem[VE + i * 512]);
      }
    }
    // ---- stage K(mt+1) -> other buffer (12 DMA/wave) ----
    {
      const char* kt = (const char*)(khp + ((size_t)b * 2048 + ((mt + 1) & 63) * 32) * 384);
#pragma unroll
      for (int t = 0; t < 12; ++t) {
        int g = w * 4 + t / 3;
        glds16(kt + g * 3072 + kfo[(t % 3) * 2 + (g & 1)], &smem[KE(cur ^ 1) + (w * 12 + t) * 512]);
      }
    }

    // ---- S phase: separate hi/lo accumulators (4 MFMA chains) ----
    f32x4 sa[2], sb[2];
#pragma unroll
    for (int cf = 0; cf < 2; ++cf) { sa[cf] = (f32x4){0.f,0.f,0.f,0.f}; sb[cf] = (f32x4){0.f,0.f,0.f,0.f}; }
#pragma unroll
    for (int ks = 0; ks < 12; ++ks) {
#pragma unroll
      for (int cf = 0; cf < 2; ++cf) {
        const int row = cf * 16 + q15;
        const int c3 = (((ks & 1) * 4) | quad) ^ (q15 & 7);
        h16x8 bk = *(const h16x8*)&smem[KE(cur) + row * 384 + ((ks >> 1) * 8 + c3) * 8];
        sa[cf] = MF16(qfh[ks], bk, sa[cf]);
        sb[cf] = MF16(qfl[ks], bk, sb[cf]);
      }
    }
#pragma unroll
    for (int cf = 0; cf < 2; ++cf) sa[cf] += sb[cf];

    // ---- online softmax (rows = quad*4+r; reduce over q15 x cf) ----
    float al[4], p0[4], p1[4];
#pragma unroll
    for (int r = 0; r < 4; ++r) {
      float mx = rmax16(fmaxf(sa[0][r], sa[1][r]));
      float mn = fmaxf(mo[r], mx);
      al[r] = __expf(mo[r] - mn);
      mo[r] = mn;
      p0[r] = __expf(sa[0][r] - mn);
      p1[r] = __expf(sa[1][r] - mn);
      ll[r] = ll[r] * al[r] + rsum16(p0[r] + p1[r]);
    }
    // P -> LDS (wave-private, C-layout write / A-layout read)
#pragma unroll
    for (int r = 0; r < 4; ++r) {
      smem[PE + w * 640 + (quad * 4 + r) * 40 +      q15] = f2h_u(p0[r]);
      smem[PE + w * 640 + (quad * 4 + r) * 40 + 16 + q15] = f2h_u(p1[r]);
    }
    // O rescale
#pragma unroll
    for (int cf = 0; cf < 24; ++cf)
#pragma unroll
      for (int r = 0; r < 4; ++r) o[cf][r] *= al[r];

    __syncthreads();   // B: V(mt) (and K(mt+1)) DMA drained

    // ---- PV ----
    h16x8 pa = *(const h16x8*)&smem[PE + w * 640 + q15 * 40 + quad * 8];
#pragma unroll
    for (int cf = 0; cf < 24; ++cf) {
      const int d = cf * 16 + q15;
      h16x8 vb = *(const h16x8*)&smem[VE + d * 32 + ((quad ^ (d & 3)) * 8)];
      o[cf] = MF16(pa, vb, o[cf]);
    }

    __syncthreads();   // A: PV reads done -> next tile may overwrite V
  }

  // ---- epilogue: out[b][d][n] = O/l via LDS transpose (fp32) ----
  float inv[4];
#pragma unroll
  for (int r = 0; r < 4; ++r) inv[r] = 1.0f / ll[r];
  float* ot = (float*)smem;
#pragma unroll
  for (int cf = 0; cf < 24; ++cf) {
    float4 st;
    st.x = o[cf][0] * inv[0]; st.y = o[cf][1] * inv[1];
    st.z = o[cf][2] * inv[2]; st.w = o[cf][3] * inv[3];
    *(float4*)&ot[(cf * 16 + q15) * 36 + w * 16 + quad * 4] = st;
  }
  __syncthreads();
  for (int c = tid; c < 3072; c += 128) {
    int d = c >> 3, n8 = c & 7;
    *(float4*)&outp[((size_t)(b * 384 + d)) * 2048 + qt * 32 + n8 * 4] =
        *(const float4*)&ot[d * 36 + n8 * 4];
  }
}

extern "C" void kernel_launch(void* const* d_in, const int* in_sizes, int n_in,
                              void* d_out, int out_size, void* d_ws, size_t ws_size,
                              hipStream_t stream) {
  const float* pos = (const float*)d_in[0];
  const float* Wq  = (const float*)d_in[1];
  const float* bq  = (const float*)d_in[2];
  const float* Wk  = (const float*)d_in[3];
  const float* bk  = (const float*)d_in[4];
  const float* Wv  = (const float*)d_in[5];
  const float* bv  = (const float*)d_in[6];

  char* ws = (char*)d_ws;
  u16* qh = (u16*)(ws + QH_OFF);
  u16* ql = (u16*)(ws + QL_OFF);
  u16* kh = (u16*)(ws + KH_OFF);
  u16* vv = (u16*)(ws + VV_OFF);

  qkv_kernel<<<512, 256, 0, stream>>>(pos, Wq, bq, Wk, bk, Wv, bv, qh, ql, kh, vv);
  attn_kernel<<<512, 128, 0, stream>>>(qh, ql, kh, vv, (float*)d_out);
}